// Round 19
// baseline (1097.335 us; speedup 1.0000x reference)
//
#include <hip/hip_runtime.h>
#include <hip/hip_fp16.h>

#define NB   256
#define TT   1024
#define II   64
#define NT   512

typedef _Float16 f16;
typedef _Float16 f16x4 __attribute__((ext_vector_type(4)));
typedef _Float16 hf8 __attribute__((ext_vector_type(8)));
typedef float    ff4 __attribute__((ext_vector_type(4)));

__device__ __forceinline__ float rcp_fast(float x){
    float r; asm("v_rcp_f32 %0, %1" : "=v"(r) : "v"(x)); return r;
}
__device__ __forceinline__ float exp2_fast(float x){
    float r; asm("v_exp_f32 %0, %1" : "=v"(r) : "v"(x)); return r;
}
__device__ __forceinline__ float sigm(float x){
    return rcp_fast(1.0f + exp2_fast(x * -1.44269504f));
}
__device__ __forceinline__ float tanh_f(float x){
    return fmaf(-2.0f, rcp_fast(1.0f + exp2_fast(x * 2.88539008f)), 1.0f);
}
__device__ __forceinline__ hf8 cvt8(float4 a, float4 b){
    hf8 r;
    r[0]=(f16)a.x; r[1]=(f16)a.y; r[2]=(f16)a.z; r[3]=(f16)a.w;
    r[4]=(f16)b.x; r[5]=(f16)b.y; r[6]=(f16)b.z; r[7]=(f16)b.w;
    return r;
}
__device__ __forceinline__ hf8 ldw8(const float* src){
    float4 a = *(const float4*)src;
    float4 b = *(const float4*)(src + 4);
    return cvt8(a, b);
}
__device__ __forceinline__ void wait_ge(volatile int* p, int tgt){
    while (*p < tgt) __builtin_amdgcn_s_sleep(1);
}

// R19 = R15 data layout (proven 817us, no spill) with the block barrier
// replaced by producer/consumer group sync:
//  - waves 0-3 (L1, 8 tiles x 4 h-kt + xg consume) sync on h1cnt only
//  - waves 4-7 (L2, 4 tiles x 6 kt) trail self-paced on h1cnt/h2cnt
//  - h1ring[4], h2ring[4]: 4-deep, skew-safe (intra-group skew<=1, L1 leads
//    L2 by <=3 via lag guard h2cnt>=4*(t-3); chunk guard at trow==0 covers
//    L2's share of the xg burst)
//  - L2 computes all 1024 steps (h2(-1)=0 ring-init): no t==0 case, no epilogue
// Anti-phase goal: L2's MFMA clusters fill L1's LDS/VALU windows since the
// groups are no longer barrier-aligned. setprio kept on L2 clusters.
// Gate-interleaved tiles + C/D mapping verified R5-R18. xg[2][16][520] f16
// dbuf holds Wih1*x+bias1 (GEMM, timestep=B-column), burst every 16 steps
// on all 8 waves (4 tiles x 2 kt each).

__launch_bounds__(NT, 2)
__global__ void lstm_mfma(const float* __restrict__ x,
                          const float* __restrict__ Wih1, const float* __restrict__ Whh1,
                          const float* __restrict__ bih1, const float* __restrict__ bhh1,
                          const float* __restrict__ Wih2, const float* __restrict__ Whh2,
                          const float* __restrict__ bih2, const float* __restrict__ bhh2,
                          const float* __restrict__ W1,   const float* __restrict__ b1,
                          const float* __restrict__ W2,   const float* __restrict__ b2,
                          float* __restrict__ out)
{
    __shared__ __align__(16) f16 xg[2][16][520];   // 33 KB
    __shared__ __align__(16) f16 h1ring[4][128];
    __shared__ __align__(16) f16 h2ring[4][64];
    __shared__ int cnt[2];                         // [0]=h1cnt, [1]=h2cnt
    __shared__ float headbuf[32];

    const int j    = threadIdx.x;      // 0..511
    const int b    = blockIdx.x;
    const int wave = j >> 6;           // 0..7
    const int lane = j & 63;
    const int rho  = lane & 15;
    const int kg   = lane >> 4;        // 0..3
    const bool l2w = (wave >= 4);
    const int  wv  = l2w ? (wave - 4) : wave;

    const float* xb = x + (size_t)b * TT * II;

    // chunk-0 x loads first (all waves; latency covered by weight loading)
    float4 xl0, xl1, xl2, xl3;
    {
        const float* xp = xb + (size_t)rho * II + kg*8;
        xl0 = *(const float4*)xp;       xl1 = *(const float4*)(xp + 4);
        xl2 = *(const float4*)(xp + 32);xl3 = *(const float4*)(xp + 36);
    }

    // ---------- weights ----------
    hf8 A[32];                          // L1: A[i*4+kt] i<8 | L2: A[i*6+kt] i<4
    float b2l0 = 0.f, b2l1 = 0.f, b2l2 = 0.f, b2l3 = 0.f;
    if (!l2w){
        #pragma unroll
        for (int i = 0; i < 8; ++i){
            const int tau = 8*wv + i;
            const int R   = (rho & 3)*128 + 4*tau + (rho >> 2);
            #pragma unroll
            for (int kt = 0; kt < 4; ++kt)
                A[i*4 + kt] = ldw8(Whh1 + R*128 + 32*kt + kg*8);
        }
    } else {
        #pragma unroll
        for (int i = 0; i < 4; ++i){
            const int tau2 = 4*wv + i;
            const int R    = (rho & 3)*64 + 4*tau2 + (rho >> 2);
            #pragma unroll
            for (int kt = 0; kt < 6; ++kt)
                A[i*6 + kt] = ldw8((kt < 4) ? (Wih2 + R*128 + 32*kt + kg*8)
                                            : (Whh2 + R*64  + 32*(kt-4) + kg*8));
        }
        const int u2 = 4*(4*wv + (rho & 3)) + kg;   // own unit (clamped dup)
        b2l0 = bih2[u2]       + bhh2[u2];
        b2l1 = bih2[64 + u2]  + bhh2[64 + u2];
        b2l2 = bih2[128 + u2] + bhh2[128 + u2];
        b2l3 = bih2[192 + u2] + bhh2[192 + u2];
    }
    // GEMM weights: 4 tiles per wave (32 total), K=64 (2 kkt)
    hf8 AX[8];
    ff4 biasX[4];
    #pragma unroll
    for (int i = 0; i < 4; ++i){
        const int tx = 4*wave + i;
        const int Rx = (rho & 3)*128 + 4*tx + (rho >> 2);
        AX[i*2 + 0] = ldw8(Wih1 + Rx*64 + kg*8);
        AX[i*2 + 1] = ldw8(Wih1 + Rx*64 + 32 + kg*8);
        #pragma unroll
        for (int r = 0; r < 4; ++r){
            const int Rb = r*128 + 4*tx + kg;
            biasX[i][r] = bih1[Rb] + bhh1[Rb];
        }
    }

    if (j == 0){ cnt[0] = 0; cnt[1] = 0; }
    if (j < 128) h1ring[3][j] = (f16)0.0f;          // h1(-1)
    if (j < 64)  h2ring[3][j] = (f16)0.0f;          // h2(-1)

    // ---------- prologue GEMM: xg chunk 0 (all 8 waves) ----------
    {
        hf8 xh0 = cvt8(xl0, xl1);
        hf8 xh1 = cvt8(xl2, xl3);
        #pragma unroll
        for (int i = 0; i < 4; ++i){
            ff4 g = __builtin_amdgcn_mfma_f32_16x16x32_f16(AX[i*2+0], xh0, biasX[i], 0, 0, 0);
            g     = __builtin_amdgcn_mfma_f32_16x16x32_f16(AX[i*2+1], xh1, g,        0, 0, 0);
            const int uX = 4*(4*wave + i) + kg;
            f16x4 w; w[0]=(f16)g[0]; w[1]=(f16)g[1]; w[2]=(f16)g[2]; w[3]=(f16)g[3];
            *(f16x4*)&xg[0][rho][uX*4] = w;
        }
    }
    __syncthreads();                   // single barrier: init complete

    volatile int* h1c = &cnt[0];
    volatile int* h2c = &cnt[1];
    float c = 0.0f;

    if (!l2w){
        // ================= L1 group (waves 0-3) =================
        for (int t = 0; t < TT; ++t){
            const int trow = t & 15;
            const int cb   = (t >> 4) & 1;

            wait_ge(h1c, 4*t);                          // peers done step t-1
            if (trow == 0 && t > 0) wait_ge(h2c, 4*t);  // L2 burst for this chunk
            else if (t >= 4)        wait_ge(h2c, 4*(t-3)); // ring lag guard
            __threadfence_block();

            const bool stage = (trow == 15) && (t + 1 < TT);
            if (stage){
                const float* xp = xb + (size_t)(t + 1 + rho) * II + kg*8;
                xl0 = *(const float4*)xp;       xl1 = *(const float4*)(xp + 4);
                xl2 = *(const float4*)(xp + 32);xl3 = *(const float4*)(xp + 36);
            }

            const int myUm = 4*(8*wv + (rho & 7)) + kg;
            f16x4 xv = *(const f16x4*)&xg[cb][trow][myUm*4];

            const f16* h1p = h1ring[(t - 1) & 3];
            hf8 bf0 = *(const hf8*)(h1p      + kg*8);
            hf8 bf1 = *(const hf8*)(h1p + 32 + kg*8);
            hf8 bf2 = *(const hf8*)(h1p + 64 + kg*8);
            hf8 bf3 = *(const hf8*)(h1p + 96 + kg*8);

            const ff4 zz = {0.0f, 0.0f, 0.0f, 0.0f};
            ff4 acc[8];
            #pragma unroll
            for (int i = 0; i < 8; ++i)
                acc[i] = __builtin_amdgcn_mfma_f32_16x16x32_f16(A[i*4+0], bf0, zz, 0, 0, 0);
            #pragma unroll
            for (int i = 0; i < 8; ++i)
                acc[i] = __builtin_amdgcn_mfma_f32_16x16x32_f16(A[i*4+1], bf1, acc[i], 0, 0, 0);
            #pragma unroll
            for (int i = 0; i < 8; ++i)
                acc[i] = __builtin_amdgcn_mfma_f32_16x16x32_f16(A[i*4+2], bf2, acc[i], 0, 0, 0);
            #pragma unroll
            for (int i = 0; i < 8; ++i)
                acc[i] = __builtin_amdgcn_mfma_f32_16x16x32_f16(A[i*4+3], bf3, acc[i], 0, 0, 0);

            ff4 s0 = (rho & 1) ? acc[1] : acc[0];
            ff4 s1 = (rho & 1) ? acc[3] : acc[2];
            ff4 s2 = (rho & 1) ? acc[5] : acc[4];
            ff4 s3 = (rho & 1) ? acc[7] : acc[6];
            ff4 u0 = (rho & 2) ? s1 : s0;
            ff4 u1 = (rho & 2) ? s3 : s2;
            ff4 qd = (rho & 4) ? u1 : u0;

            float ig = sigm(qd[0] + (float)xv[0]);
            float fg = sigm(qd[1] + (float)xv[1]);
            float gg = tanh_f(qd[2] + (float)xv[2]);
            float og = sigm(qd[3] + (float)xv[3]);
            c = fg*c + ig*gg;
            float hv = og * tanh_f(c);
            if (rho < 8) h1ring[t & 3][4*(8*wv + rho) + kg] = (f16)hv;

            if (stage){
                hf8 xh0 = cvt8(xl0, xl1);
                hf8 xh1 = cvt8(xl2, xl3);
                #pragma unroll
                for (int i = 0; i < 4; ++i){
                    ff4 g = __builtin_amdgcn_mfma_f32_16x16x32_f16(AX[i*2+0], xh0, biasX[i], 0, 0, 0);
                    g     = __builtin_amdgcn_mfma_f32_16x16x32_f16(AX[i*2+1], xh1, g,        0, 0, 0);
                    const int uX = 4*(4*wave + i) + kg;
                    f16x4 w; w[0]=(f16)g[0]; w[1]=(f16)g[1]; w[2]=(f16)g[2]; w[3]=(f16)g[3];
                    *(f16x4*)&xg[cb ^ 1][rho][uX*4] = w;
                }
            }

            __threadfence_block();
            if (lane == 0) atomicAdd(&cnt[0], 1);
        }
    } else {
        // ================= L2 group (waves 4-7), trails L1 =================
        for (int s = 0; s < TT; ++s){
            const int trow = s & 15;

            wait_ge(h1c, 4*(s + 1));                    // h1(s) ready
            wait_ge(h2c, 4*s);                          // peers done step s-1
            __threadfence_block();

            const bool stage = (trow == 15) && (s + 1 < TT);
            if (stage){
                const float* xp = xb + (size_t)(s + 1 + rho) * II + kg*8;
                xl0 = *(const float4*)xp;       xl1 = *(const float4*)(xp + 4);
                xl2 = *(const float4*)(xp + 32);xl3 = *(const float4*)(xp + 36);
            }

            const f16* h1p = h1ring[s & 3];
            const f16* h2p = h2ring[(s - 1) & 3];
            hf8 bf0 = *(const hf8*)(h1p      + kg*8);
            hf8 bf1 = *(const hf8*)(h1p + 32 + kg*8);
            hf8 bf2 = *(const hf8*)(h1p + 64 + kg*8);
            hf8 bf3 = *(const hf8*)(h1p + 96 + kg*8);
            hf8 bf4 = *(const hf8*)(h2p      + kg*8);
            hf8 bf5 = *(const hf8*)(h2p + 32 + kg*8);

            const ff4 zz = {0.0f, 0.0f, 0.0f, 0.0f};
            ff4 acc[4];
            __builtin_amdgcn_s_setprio(1);
            #pragma unroll
            for (int i = 0; i < 4; ++i)
                acc[i] = __builtin_amdgcn_mfma_f32_16x16x32_f16(A[i*6+0], bf0, zz, 0, 0, 0);
            #pragma unroll
            for (int kt = 1; kt < 6; ++kt){
                hf8 bb = (kt==1)?bf1:(kt==2)?bf2:(kt==3)?bf3:(kt==4)?bf4:bf5;
                #pragma unroll
                for (int i = 0; i < 4; ++i)
                    acc[i] = __builtin_amdgcn_mfma_f32_16x16x32_f16(A[i*6+kt], bb, acc[i], 0, 0, 0);
            }
            __builtin_amdgcn_s_setprio(0);

            ff4 s0 = (rho & 1) ? acc[1] : acc[0];
            ff4 s1 = (rho & 1) ? acc[3] : acc[2];
            ff4 qd = (rho & 2) ? s1 : s0;

            float ig = sigm(qd[0] + b2l0);
            float fg = sigm(qd[1] + b2l1);
            float gg = tanh_f(qd[2] + b2l2);
            float og = sigm(qd[3] + b2l3);
            c = fg*c + ig*gg;
            float hv = og * tanh_f(c);
            if (rho < 4) h2ring[s & 3][4*(4*wv + rho) + kg] = (f16)hv;

            if (stage){
                hf8 xh0 = cvt8(xl0, xl1);
                hf8 xh1 = cvt8(xl2, xl3);
                const int cb = (s >> 4) & 1;
                #pragma unroll
                for (int i = 0; i < 4; ++i){
                    ff4 g = __builtin_amdgcn_mfma_f32_16x16x32_f16(AX[i*2+0], xh0, biasX[i], 0, 0, 0);
                    g     = __builtin_amdgcn_mfma_f32_16x16x32_f16(AX[i*2+1], xh1, g,        0, 0, 0);
                    const int uX = 4*(4*wave + i) + kg;
                    f16x4 w; w[0]=(f16)g[0]; w[1]=(f16)g[1]; w[2]=(f16)g[2]; w[3]=(f16)g[3];
                    *(f16x4*)&xg[cb ^ 1][rho][uX*4] = w;
                }
            }

            __threadfence_block();
            if (lane == 0) atomicAdd(&cnt[1], 1);
        }
    }

    __syncthreads();

    // ---- MLP head (final h2 = h2ring[(TT-1)&3] = h2ring[3]) ----
    if (j < 32){
        float a = b1[j];
        const float* w = W1 + j*64;
        #pragma unroll
        for (int k = 0; k < 64; ++k) a = fmaf(w[k], (float)h2ring[3][k], a);
        headbuf[j] = sigm(a);
    }
    __syncthreads();
    if (j == 0){
        float a = b2[0];
        #pragma unroll
        for (int k = 0; k < 32; ++k) a = fmaf(W2[k], headbuf[k], a);
        out[b] = sigm(a);
    }
}

extern "C" void kernel_launch(void* const* d_in, const int* in_sizes, int n_in,
                              void* d_out, int out_size, void* d_ws, size_t ws_size,
                              hipStream_t stream)
{
    (void)in_sizes; (void)n_in; (void)d_ws; (void)ws_size; (void)out_size;
    lstm_mfma<<<NB, NT, 0, stream>>>(
        (const float*)d_in[0],
        (const float*)d_in[1], (const float*)d_in[2],
        (const float*)d_in[3], (const float*)d_in[4],
        (const float*)d_in[5], (const float*)d_in[6],
        (const float*)d_in[7], (const float*)d_in[8],
        (const float*)d_in[9], (const float*)d_in[10],
        (const float*)d_in[11], (const float*)d_in[12],
        (float*)d_out);
}

// Round 20
// 922.926 us; speedup vs baseline: 1.1890x; 1.1890x over previous
//
#include <hip/hip_runtime.h>
#include <hip/hip_fp16.h>

#define NB   256
#define TT   1024
#define II   64
#define NT   512

typedef _Float16 f16;
typedef _Float16 f16x4 __attribute__((ext_vector_type(4)));
typedef _Float16 hf8 __attribute__((ext_vector_type(8)));
typedef float    ff4 __attribute__((ext_vector_type(4)));

__device__ __forceinline__ float rcp_fast(float x){
    float r; asm("v_rcp_f32 %0, %1" : "=v"(r) : "v"(x)); return r;
}
__device__ __forceinline__ float exp2_fast(float x){
    float r; asm("v_exp_f32 %0, %1" : "=v"(r) : "v"(x)); return r;
}
__device__ __forceinline__ float sigm(float x){
    return rcp_fast(1.0f + exp2_fast(x * -1.44269504f));
}
__device__ __forceinline__ float tanh_f(float x){
    return fmaf(-2.0f, rcp_fast(1.0f + exp2_fast(x * 2.88539008f)), 1.0f);
}
__device__ __forceinline__ hf8 cvt8(float4 a, float4 b){
    hf8 r;
    r[0]=(f16)a.x; r[1]=(f16)a.y; r[2]=(f16)a.z; r[3]=(f16)a.w;
    r[4]=(f16)b.x; r[5]=(f16)b.y; r[6]=(f16)b.z; r[7]=(f16)b.w;
    return r;
}
__device__ __forceinline__ hf8 ldw8(const float* src){
    float4 a = *(const float4*)src;
    float4 b = *(const float4*)(src + 4);
    return cvt8(a, b);
}

// R20: cut the matrix floor 224 -> 168 MFMA/step by batching L2's h1-input
// through time (p2g GEMM), since only h2 is truly recurrent for L2.
//  - L1 (step t):   h-part 32 tiles x 4 kt; x-part via xg GEMM (R15-proven).
//  - L2 (step t-17): h2-part 16 tiles x 2 kt; h1-part via p2g GEMM:
//    every 16 steps, P2 = Wih2*h1(s)+b2 for 16 steps, time = B-columns,
//    from a 32-deep h1 ring.  L2 trails L1 by 17 steps; 17-iter epilogue.
//  - all 8 waves identical mix: 4 L1 tiles + 2 L2 tiles + 4 xg + 2 p2g tiles.
//  - unified activation: every lane does act(qd + pre), pre scatter-read from
//    xg (lanes rho<8) or p2g (rho>=8); biases folded into GEMM C-init.
// Gate-interleaved tiles + C/D mapping verified R5-R19: gate-row
// R=(rho&3)*H + 4*tau + (rho>>2); C/D row=kg*4+reg; B cols duplicated.

__launch_bounds__(NT, 2)
__global__ void lstm_mfma(const float* __restrict__ x,
                          const float* __restrict__ Wih1, const float* __restrict__ Whh1,
                          const float* __restrict__ bih1, const float* __restrict__ bhh1,
                          const float* __restrict__ Wih2, const float* __restrict__ Whh2,
                          const float* __restrict__ bih2, const float* __restrict__ bhh2,
                          const float* __restrict__ W1,   const float* __restrict__ b1,
                          const float* __restrict__ W2,   const float* __restrict__ b2,
                          float* __restrict__ out)
{
    __shared__ __align__(16) f16 xg[2][16][520];    // 33 KB  Wih1*x+b1
    __shared__ __align__(16) f16 p2g[2][16][264];   // 17 KB  Wih2*h1+b2
    __shared__ __align__(16) f16 h1ring[32][136];   // 8.7 KB h1 history
    __shared__ __align__(16) f16 h2buf[2][72];
    __shared__ float headbuf[32];

    const int j    = threadIdx.x;      // 0..511
    const int b    = blockIdx.x;
    const int wave = j >> 6;           // 0..7
    const int lane = j & 63;
    const int rho  = lane & 15;
    const int kg   = lane >> 4;        // 0..3

    const float* xb = x + (size_t)b * TT * II;

    // chunk-0 x loads first (latency covered by weight loading)
    float4 xl0, xl1, xl2, xl3;
    {
        const float* xp = xb + (size_t)rho * II + kg*8;
        xl0 = *(const float4*)xp;       xl1 = *(const float4*)(xp + 4);
        xl2 = *(const float4*)(xp + 32);xl3 = *(const float4*)(xp + 36);
    }

    // ---------- weights ----------
    hf8 A1[16];     // L1 Whh1: [i*4+kt], i<4
    hf8 A2[4];      // L2 Whh2: [i*2+kt], i<2
    hf8 AX[8];      // xg GEMM Wih1: [i*2+kkt], i<4
    hf8 AP[8];      // p2g GEMM Wih2: [i*4+kt], i<2
    ff4 biasX[4], biasP[2];
    #pragma unroll
    for (int i = 0; i < 4; ++i){
        const int tau = 4*wave + i;
        const int R   = (rho & 3)*128 + 4*tau + (rho >> 2);
        #pragma unroll
        for (int kt = 0; kt < 4; ++kt)
            A1[i*4 + kt] = ldw8(Whh1 + R*128 + 32*kt + kg*8);
        AX[i*2 + 0] = ldw8(Wih1 + R*64 + kg*8);
        AX[i*2 + 1] = ldw8(Wih1 + R*64 + 32 + kg*8);
        #pragma unroll
        for (int r = 0; r < 4; ++r){
            const int Rb = r*128 + 4*tau + kg;
            biasX[i][r] = bih1[Rb] + bhh1[Rb];
        }
    }
    #pragma unroll
    for (int i = 0; i < 2; ++i){
        const int tau2 = 2*wave + i;
        const int R2   = (rho & 3)*64 + 4*tau2 + (rho >> 2);
        #pragma unroll
        for (int kt = 0; kt < 2; ++kt)
            A2[i*2 + kt] = ldw8(Whh2 + R2*64 + 32*kt + kg*8);
        #pragma unroll
        for (int kt = 0; kt < 4; ++kt)
            AP[i*4 + kt] = ldw8(Wih2 + R2*128 + 32*kt + kg*8);
        #pragma unroll
        for (int r = 0; r < 4; ++r){
            const int Rb = r*64 + 4*tau2 + kg;
            biasP[i][r] = bih2[Rb] + bhh2[Rb];
        }
    }

    if (j < 128) h1ring[31][j] = (f16)0.0f;     // h1(-1)
    if (j < 64)  h2buf[1][j]  = (f16)0.0f;      // h2(-1)

    // ---------- prologue: xg chunk 0 ----------
    {
        hf8 xh0 = cvt8(xl0, xl1);
        hf8 xh1 = cvt8(xl2, xl3);
        #pragma unroll
        for (int i = 0; i < 4; ++i){
            ff4 g = __builtin_amdgcn_mfma_f32_16x16x32_f16(AX[i*2+0], xh0, biasX[i], 0, 0, 0);
            g     = __builtin_amdgcn_mfma_f32_16x16x32_f16(AX[i*2+1], xh1, g,        0, 0, 0);
            const int uX = 4*(4*wave + i) + kg;
            f16x4 w; w[0]=(f16)g[0]; w[1]=(f16)g[1]; w[2]=(f16)g[2]; w[3]=(f16)g[3];
            *(f16x4*)&xg[0][rho][uX*4] = w;
        }
    }
    __syncthreads();

    const bool isl2 = (rho >= 8);
    const int  myU1 = 4*(4*wave + (rho & 3)) + kg;
    const int  myU2 = 4*(2*wave + (rho & 1)) + kg;
    const ff4  zz   = {0.0f, 0.0f, 0.0f, 0.0f};
    float c = 0.0f;

    for (int t = 0; t < TT + 17; ++t){
        const int trow = t & 15;
        const int s    = t - 17;

        // x loads for xg burst (same iteration; latency hides under MFMAs)
        const bool stage = (trow == 15) && (t + 1 < TT);
        if (stage){
            const float* xp = xb + (size_t)(t + 1 + rho) * II + kg*8;
            xl0 = *(const float4*)xp;       xl1 = *(const float4*)(xp + 4);
            xl2 = *(const float4*)(xp + 32);xl3 = *(const float4*)(xp + 36);
        }

        ff4 qd1 = zz, qd2 = zz;

        // ---- L1 recurrent MFMA (step t) ----
        if (t < TT){
            const f16* h1p = h1ring[(t - 1) & 31];
            hf8 bf0 = *(const hf8*)(h1p      + kg*8);
            hf8 bf1 = *(const hf8*)(h1p + 32 + kg*8);
            hf8 bf2 = *(const hf8*)(h1p + 64 + kg*8);
            hf8 bf3 = *(const hf8*)(h1p + 96 + kg*8);
            ff4 a[4];
            #pragma unroll
            for (int i = 0; i < 4; ++i)
                a[i] = __builtin_amdgcn_mfma_f32_16x16x32_f16(A1[i*4+0], bf0, zz, 0, 0, 0);
            #pragma unroll
            for (int i = 0; i < 4; ++i)
                a[i] = __builtin_amdgcn_mfma_f32_16x16x32_f16(A1[i*4+1], bf1, a[i], 0, 0, 0);
            #pragma unroll
            for (int i = 0; i < 4; ++i)
                a[i] = __builtin_amdgcn_mfma_f32_16x16x32_f16(A1[i*4+2], bf2, a[i], 0, 0, 0);
            #pragma unroll
            for (int i = 0; i < 4; ++i)
                a[i] = __builtin_amdgcn_mfma_f32_16x16x32_f16(A1[i*4+3], bf3, a[i], 0, 0, 0);
            ff4 s0 = (rho & 1) ? a[1] : a[0];
            ff4 s1 = (rho & 1) ? a[3] : a[2];
            qd1    = (rho & 2) ? s1 : s0;
        }

        // ---- L2 recurrent MFMA (step s = t-17) ----
        if (t >= 17){
            const f16* h2p = h2buf[(s - 1) & 1];
            hf8 c0 = *(const hf8*)(h2p      + kg*8);
            hf8 c1 = *(const hf8*)(h2p + 32 + kg*8);
            ff4 a2[2];
            #pragma unroll
            for (int i = 0; i < 2; ++i)
                a2[i] = __builtin_amdgcn_mfma_f32_16x16x32_f16(A2[i*2+0], c0, zz, 0, 0, 0);
            #pragma unroll
            for (int i = 0; i < 2; ++i)
                a2[i] = __builtin_amdgcn_mfma_f32_16x16x32_f16(A2[i*2+1], c1, a2[i], 0, 0, 0);
            qd2 = (rho & 1) ? a2[1] : a2[0];
        }

        // ---- p2g burst: P2 for steps [t-16, t) (h1 all written) ----
        if (trow == 0 && t >= 16 && t <= TT){
            const int base = t - 16;
            const int pb   = ((t >> 4) - 1) & 1;
            const f16* hp  = h1ring[(base + rho) & 31];
            hf8 bp0 = *(const hf8*)(hp      + kg*8);
            hf8 bp1 = *(const hf8*)(hp + 32 + kg*8);
            hf8 bp2 = *(const hf8*)(hp + 64 + kg*8);
            hf8 bp3 = *(const hf8*)(hp + 96 + kg*8);
            #pragma unroll
            for (int i = 0; i < 2; ++i){
                ff4 g = __builtin_amdgcn_mfma_f32_16x16x32_f16(AP[i*4+0], bp0, biasP[i], 0, 0, 0);
                g     = __builtin_amdgcn_mfma_f32_16x16x32_f16(AP[i*4+1], bp1, g, 0, 0, 0);
                g     = __builtin_amdgcn_mfma_f32_16x16x32_f16(AP[i*4+2], bp2, g, 0, 0, 0);
                g     = __builtin_amdgcn_mfma_f32_16x16x32_f16(AP[i*4+3], bp3, g, 0, 0, 0);
                const int uP = 4*(2*wave + i) + kg;
                f16x4 w; w[0]=(f16)g[0]; w[1]=(f16)g[1]; w[2]=(f16)g[2]; w[3]=(f16)g[3];
                *(f16x4*)&p2g[pb][rho][uP*4] = w;
            }
        }

        // ---- xg burst for next chunk ----
        if (stage){
            hf8 xh0 = cvt8(xl0, xl1);
            hf8 xh1 = cvt8(xl2, xl3);
            const int cb = (t >> 4) & 1;
            #pragma unroll
            for (int i = 0; i < 4; ++i){
                ff4 g = __builtin_amdgcn_mfma_f32_16x16x32_f16(AX[i*2+0], xh0, biasX[i], 0, 0, 0);
                g     = __builtin_amdgcn_mfma_f32_16x16x32_f16(AX[i*2+1], xh1, g,        0, 0, 0);
                const int uX = 4*(4*wave + i) + kg;
                f16x4 w; w[0]=(f16)g[0]; w[1]=(f16)g[1]; w[2]=(f16)g[2]; w[3]=(f16)g[3];
                *(f16x4*)&xg[cb ^ 1][rho][uX*4] = w;
            }
        }

        // ---- unified activation: act(qd + pre) ----
        {
            const bool active = isl2 ? (t >= 17) : (t < TT);
            if (active){
                const f16* pbase = isl2
                    ? &p2g[(s >> 4) & 1][s & 15][myU2*4]
                    : &xg[(t >> 4) & 1][trow][myU1*4];
                f16x4 pre = *(const f16x4*)pbase;
                ff4 qd = isl2 ? qd2 : qd1;
                float ig = sigm(qd[0] + (float)pre[0]);
                float fg = sigm(qd[1] + (float)pre[1]);
                float tg = tanh_f(qd[2] + (float)pre[2]);
                float og = sigm(qd[3] + (float)pre[3]);
                c = fg*c + ig*tg;
                float hv = og * tanh_f(c);
                if (!isl2){
                    if (rho < 4) h1ring[t & 31][myU1] = (f16)hv;
                } else {
                    if (rho < 10) h2buf[s & 1][myU2] = (f16)hv;
                }
            }
        }
        __syncthreads();
    }
    // h2(TT-1) is in h2buf[(TT-1)&1] = h2buf[1]

    // ---- MLP head ----
    if (j < 32){
        float a = b1[j];
        const float* w = W1 + j*64;
        #pragma unroll
        for (int k = 0; k < 64; ++k) a = fmaf(w[k], (float)h2buf[1][k], a);
        headbuf[j] = sigm(a);
    }
    __syncthreads();
    if (j == 0){
        float a = b2[0];
        #pragma unroll
        for (int k = 0; k < 32; ++k) a = fmaf(W2[k], headbuf[k], a);
        out[b] = sigm(a);
    }
}

extern "C" void kernel_launch(void* const* d_in, const int* in_sizes, int n_in,
                              void* d_out, int out_size, void* d_ws, size_t ws_size,
                              hipStream_t stream)
{
    (void)in_sizes; (void)n_in; (void)d_ws; (void)ws_size; (void)out_size;
    lstm_mfma<<<NB, NT, 0, stream>>>(
        (const float*)d_in[0],
        (const float*)d_in[1], (const float*)d_in[2],
        (const float*)d_in[3], (const float*)d_in[4],
        (const float*)d_in[5], (const float*)d_in[6],
        (const float*)d_in[7], (const float*)d_in[8],
        (const float*)d_in[9], (const float*)d_in[10],
        (const float*)d_in[11], (const float*)d_in[12],
        (float*)d_out);
}

// Round 21
// 818.894 us; speedup vs baseline: 1.3400x; 1.1270x over previous
//
#include <hip/hip_runtime.h>
#include <hip/hip_fp16.h>

#define NB   256
#define TT   1024
#define II   64
#define NT   512

typedef _Float16 f16;
typedef _Float16 f16x4 __attribute__((ext_vector_type(4)));
typedef _Float16 hf8 __attribute__((ext_vector_type(8)));
typedef float    ff4 __attribute__((ext_vector_type(4)));

__device__ __forceinline__ float rcp_fast(float x){
    float r; asm("v_rcp_f32 %0, %1" : "=v"(r) : "v"(x)); return r;
}
__device__ __forceinline__ float exp2_fast(float x){
    float r; asm("v_exp_f32 %0, %1" : "=v"(r) : "v"(x)); return r;
}
__device__ __forceinline__ float sigm(float x){
    return rcp_fast(1.0f + exp2_fast(x * -1.44269504f));
}
__device__ __forceinline__ float tanh_f(float x){
    return fmaf(-2.0f, rcp_fast(1.0f + exp2_fast(x * 2.88539008f)), 1.0f);
}
__device__ __forceinline__ hf8 cvt8(float4 a, float4 b){
    hf8 r;
    r[0]=(f16)a.x; r[1]=(f16)a.y; r[2]=(f16)a.z; r[3]=(f16)a.w;
    r[4]=(f16)b.x; r[5]=(f16)b.y; r[6]=(f16)b.z; r[7]=(f16)b.w;
    return r;
}
__device__ __forceinline__ hf8 ldw8(const float* src){
    float4 a = *(const float4*)src;
    float4 b = *(const float4*)(src + 4);
    return cvt8(a, b);
}

// FINAL: R15 structure (best verified: 817us, no spill).
//  - 8 waves, 2/SIMD, each SIMD hosts {1 L1 wave, 1 L2 wave}.
//  - Waves 0-3: L1, 8 tiles x 4 h-kt; x-contribution via xg GEMM
//    (Wih1*x+bias1 for 16 timesteps as B-columns, burst every 16 steps).
//  - Waves 4-7: L2, 4 tiles x 6 kt ([h1;h2]), setprio(1) cluster (T5).
//  - Gate-interleaved tiles (verified R5-R20): gate-row R = (rho&3)*H +
//    4*tau + (rho>>2); C/D col=lane&15, row=kg*4+reg => lane (kg,rho)
//    holds gates i,f,g,o of unit 4*tau+kg; lanes select their tile via
//    static cndmask tree; bias added post-select (L2) / via GEMM C (L1-x).
//  - xg[2][16][520] f16 double-buffered; xg consume = per-lane f16x4
//    scatter read (rho&7 broadcast clamp for dup lanes).
// Structural limit analysis: per-step matrix floor ~1106 cyc; measured
// ~1915; six overlap/floor attacks (R16-R20) all regressed with predicted
// failure signatures -> converged at this decomposition's optimum.

__launch_bounds__(NT, 2)
__global__ void lstm_mfma(const float* __restrict__ x,
                          const float* __restrict__ Wih1, const float* __restrict__ Whh1,
                          const float* __restrict__ bih1, const float* __restrict__ bhh1,
                          const float* __restrict__ Wih2, const float* __restrict__ Whh2,
                          const float* __restrict__ bih2, const float* __restrict__ bhh2,
                          const float* __restrict__ W1,   const float* __restrict__ b1,
                          const float* __restrict__ W2,   const float* __restrict__ b2,
                          float* __restrict__ out)
{
    __shared__ __align__(16) f16 xg[2][16][520];   // 33 KB, row pad 520
    __shared__ __align__(16) f16 h1buf[2][128];
    __shared__ __align__(16) f16 h2buf[2][64];
    __shared__ float headbuf[32];

    const int j    = threadIdx.x;      // 0..511
    const int b    = blockIdx.x;
    const int wave = j >> 6;           // 0..7
    const int lane = j & 63;
    const int rho  = lane & 15;
    const int kg   = lane >> 4;        // 0..3
    const bool l2w = (wave >= 4);
    const int  wv  = wave & 3;

    const float* xb = x + (size_t)b * TT * II;

    // chunk-0 x loads first (latency covered by weight loading below)
    float4 xl0, xl1, xl2, xl3;
    {
        const float* xp = xb + (size_t)rho * II + kg*8;
        xl0 = *(const float4*)xp;       xl1 = *(const float4*)(xp + 4);
        xl2 = *(const float4*)(xp + 32);xl3 = *(const float4*)(xp + 36);
    }

    // ---------- weights ----------
    hf8 A[32];                          // L1: A[i*4+kt] i<8 | L2: A[i*6+kt] i<4
    float b2l0 = 0.f, b2l1 = 0.f, b2l2 = 0.f, b2l3 = 0.f;   // L2 bias (own unit)
    if (!l2w){
        #pragma unroll
        for (int i = 0; i < 8; ++i){
            const int tau = 8*wv + i;
            const int R   = (rho & 3)*128 + 4*tau + (rho >> 2);
            #pragma unroll
            for (int kt = 0; kt < 4; ++kt)
                A[i*4 + kt] = ldw8(Whh1 + R*128 + 32*kt + kg*8);
        }
    } else {
        #pragma unroll
        for (int i = 0; i < 4; ++i){
            const int tau2 = 4*wv + i;
            const int R    = (rho & 3)*64 + 4*tau2 + (rho >> 2);
            #pragma unroll
            for (int kt = 0; kt < 6; ++kt)
                A[i*6 + kt] = ldw8((kt < 4) ? (Wih2 + R*128 + 32*kt + kg*8)
                                            : (Whh2 + R*64  + 32*(kt-4) + kg*8));
        }
        const int u2 = 4*(4*wv + (rho & 3)) + kg;   // own unit (clamped dup)
        b2l0 = bih2[u2]       + bhh2[u2];
        b2l1 = bih2[64 + u2]  + bhh2[64 + u2];
        b2l2 = bih2[128 + u2] + bhh2[128 + u2];
        b2l3 = bih2[192 + u2] + bhh2[192 + u2];
    }
    // GEMM weights: 4 tiles per wave (32 total), K=64 (2 kkt)
    hf8 AX[8];
    ff4 biasX[4];
    #pragma unroll
    for (int i = 0; i < 4; ++i){
        const int tx = 4*wave + i;
        const int Rx = (rho & 3)*128 + 4*tx + (rho >> 2);
        AX[i*2 + 0] = ldw8(Wih1 + Rx*64 + kg*8);
        AX[i*2 + 1] = ldw8(Wih1 + Rx*64 + 32 + kg*8);
        #pragma unroll
        for (int r = 0; r < 4; ++r){
            const int Rb = r*128 + 4*tx + kg;
            biasX[i][r] = bih1[Rb] + bhh1[Rb];
        }
    }

    if (j < 128) h1buf[0][j] = (f16)0.0f;
    if (j < 64)  h2buf[0][j] = (f16)0.0f;

    // ---------- prologue GEMM: xg chunk 0 (steps 0..15) ----------
    {
        hf8 xh0 = cvt8(xl0, xl1);
        hf8 xh1 = cvt8(xl2, xl3);
        #pragma unroll
        for (int i = 0; i < 4; ++i){
            ff4 g = __builtin_amdgcn_mfma_f32_16x16x32_f16(AX[i*2+0], xh0, biasX[i], 0, 0, 0);
            g     = __builtin_amdgcn_mfma_f32_16x16x32_f16(AX[i*2+1], xh1, g,        0, 0, 0);
            const int uX = 4*(4*wave + i) + kg;
            f16x4 w; w[0]=(f16)g[0]; w[1]=(f16)g[1]; w[2]=(f16)g[2]; w[3]=(f16)g[3];
            *(f16x4*)&xg[0][rho][uX*4] = w;
        }
    }
    __syncthreads();

    const ff4 zz = {0.0f, 0.0f, 0.0f, 0.0f};
    float c = 0.0f;
    int cur = 0;
    for (int t = 0; t < TT; ++t){
        const int trow = t & 15;
        const int cb   = (t >> 4) & 1;
        const bool stage = (trow == 15) && (t + 1 < TT);

        // issue next chunk's x loads (consumed later this step, L3-resident)
        if (stage){
            const float* xp = xb + (size_t)(t + 1 + rho) * II + kg*8;
            xl0 = *(const float4*)xp;       xl1 = *(const float4*)(xp + 4);
            xl2 = *(const float4*)(xp + 32);xl3 = *(const float4*)(xp + 36);
        }

        // xg scatter read hoisted (L1 only; rho&7 clamp -> broadcast dup)
        f16x4 xv = {};
        if (!l2w){
            const int myUm = 4*(8*wv + (rho & 7)) + kg;
            xv = *(const f16x4*)&xg[cb][trow][myUm*4];
        }

        const f16* h1c = h1buf[cur];
        hf8 bf0 = *(const hf8*)(h1c      + kg*8);
        hf8 bf1 = *(const hf8*)(h1c + 32 + kg*8);
        hf8 bf2 = *(const hf8*)(h1c + 64 + kg*8);
        hf8 bf3 = *(const hf8*)(h1c + 96 + kg*8);

        ff4 qd;
        if (!l2w){
            ff4 acc[8];
            #pragma unroll
            for (int i = 0; i < 8; ++i)
                acc[i] = __builtin_amdgcn_mfma_f32_16x16x32_f16(A[i*4+0], bf0, zz, 0, 0, 0);
            #pragma unroll
            for (int i = 0; i < 8; ++i)
                acc[i] = __builtin_amdgcn_mfma_f32_16x16x32_f16(A[i*4+1], bf1, acc[i], 0, 0, 0);
            #pragma unroll
            for (int i = 0; i < 8; ++i)
                acc[i] = __builtin_amdgcn_mfma_f32_16x16x32_f16(A[i*4+2], bf2, acc[i], 0, 0, 0);
            #pragma unroll
            for (int i = 0; i < 8; ++i)
                acc[i] = __builtin_amdgcn_mfma_f32_16x16x32_f16(A[i*4+3], bf3, acc[i], 0, 0, 0);

            ff4 s0 = (rho & 1) ? acc[1] : acc[0];
            ff4 s1 = (rho & 1) ? acc[3] : acc[2];
            ff4 s2 = (rho & 1) ? acc[5] : acc[4];
            ff4 s3 = (rho & 1) ? acc[7] : acc[6];
            ff4 u0 = (rho & 2) ? s1 : s0;
            ff4 u1 = (rho & 2) ? s3 : s2;
            qd     = (rho & 4) ? u1 : u0;
        } else {
            const f16* h2c = h2buf[cur];
            hf8 bf4 = *(const hf8*)(h2c      + kg*8);
            hf8 bf5 = *(const hf8*)(h2c + 32 + kg*8);
            ff4 acc[4];
            __builtin_amdgcn_s_setprio(1);     // T5: L2 wins issue -> staggers
            #pragma unroll
            for (int i = 0; i < 4; ++i)
                acc[i] = __builtin_amdgcn_mfma_f32_16x16x32_f16(A[i*6+0], bf0, zz, 0, 0, 0);
            #pragma unroll
            for (int kt = 1; kt < 6; ++kt){
                hf8 bb = (kt==1)?bf1:(kt==2)?bf2:(kt==3)?bf3:(kt==4)?bf4:bf5;
                #pragma unroll
                for (int i = 0; i < 4; ++i)
                    acc[i] = __builtin_amdgcn_mfma_f32_16x16x32_f16(A[i*6+kt], bb, acc[i], 0, 0, 0);
            }
            __builtin_amdgcn_s_setprio(0);
            ff4 s0 = (rho & 1) ? acc[1] : acc[0];
            ff4 s1 = (rho & 1) ? acc[3] : acc[2];
            qd     = (rho & 2) ? s1 : s0;
            qd[0] += b2l0; qd[1] += b2l1; qd[2] += b2l2; qd[3] += b2l3;
        }

        // ---- GEMM burst for next chunk (all waves, t%16==15) ----
        if (stage){
            hf8 xh0 = cvt8(xl0, xl1);
            hf8 xh1 = cvt8(xl2, xl3);
            #pragma unroll
            for (int i = 0; i < 4; ++i){
                ff4 g = __builtin_amdgcn_mfma_f32_16x16x32_f16(AX[i*2+0], xh0, biasX[i], 0, 0, 0);
                g     = __builtin_amdgcn_mfma_f32_16x16x32_f16(AX[i*2+1], xh1, g,        0, 0, 0);
                const int uX = 4*(4*wave + i) + kg;
                f16x4 w; w[0]=(f16)g[0]; w[1]=(f16)g[1]; w[2]=(f16)g[2]; w[3]=(f16)g[3];
                *(f16x4*)&xg[cb ^ 1][rho][uX*4] = w;
            }
        }

        // ---- in-lane activation ----
        if (!l2w){
            float ig = sigm(qd[0] + (float)xv[0]);
            float fg = sigm(qd[1] + (float)xv[1]);
            float gg = tanh_f(qd[2] + (float)xv[2]);
            float og = sigm(qd[3] + (float)xv[3]);
            c = fg*c + ig*gg;
            float hv = og * tanh_f(c);
            if (rho < 8) h1buf[cur ^ 1][4*(8*wv + rho) + kg] = (f16)hv;
        } else {
            float hv;
            if (t > 0){
                float ig = sigm(qd[0]);
                float fg = sigm(qd[1]);
                float gg = tanh_f(qd[2]);
                float og = sigm(qd[3]);
                c = fg*c + ig*gg;
                hv = og * tanh_f(c);
            } else {
                hv = 0.0f;                 // h2_{-1}=0, c2 untouched
            }
            if (rho < 4) h2buf[cur ^ 1][4*(4*wv + rho) + kg] = (f16)hv;
        }
        __syncthreads();
        cur ^= 1;
    }
    // after loop: cur==0; h1buf[0]=h1_{TT-1}, h2buf[0]=h2_{TT-2}

    // ---- epilogue: L2 step TT-1 (waves 4-7) ----
    if (l2w){
        const f16* h1c = h1buf[0];
        const f16* h2c = h2buf[0];
        hf8 bf0 = *(const hf8*)(h1c      + kg*8);
        hf8 bf1 = *(const hf8*)(h1c + 32 + kg*8);
        hf8 bf2 = *(const hf8*)(h1c + 64 + kg*8);
        hf8 bf3 = *(const hf8*)(h1c + 96 + kg*8);
        hf8 bf4 = *(const hf8*)(h2c      + kg*8);
        hf8 bf5 = *(const hf8*)(h2c + 32 + kg*8);
        ff4 acc[4];
        const ff4 zz2 = {0.0f, 0.0f, 0.0f, 0.0f};
        #pragma unroll
        for (int i = 0; i < 4; ++i)
            acc[i] = __builtin_amdgcn_mfma_f32_16x16x32_f16(A[i*6+0], bf0, zz2, 0, 0, 0);
        #pragma unroll
        for (int kt = 1; kt < 6; ++kt){
            hf8 bb = (kt==1)?bf1:(kt==2)?bf2:(kt==3)?bf3:(kt==4)?bf4:bf5;
            #pragma unroll
            for (int i = 0; i < 4; ++i)
                acc[i] = __builtin_amdgcn_mfma_f32_16x16x32_f16(A[i*6+kt], bb, acc[i], 0, 0, 0);
        }
        ff4 s0 = (rho & 1) ? acc[1] : acc[0];
        ff4 s1 = (rho & 1) ? acc[3] : acc[2];
        ff4 qd = (rho & 2) ? s1 : s0;
        float ig = sigm(qd[0] + b2l0);
        float fg = sigm(qd[1] + b2l1);
        float gg = tanh_f(qd[2] + b2l2);
        float og = sigm(qd[3] + b2l3);
        c = fg*c + ig*gg;
        float hv = og * tanh_f(c);
        if (rho < 4) h2buf[1][4*(4*wv + rho) + kg] = (f16)hv;
    }
    __syncthreads();

    // ---- MLP head (final h2 in h2buf[1]) ----
    if (j < 32){
        float a = b1[j];
        const float* w = W1 + j*64;
        #pragma unroll
        for (int k = 0; k < 64; ++k) a = fmaf(w[k], (float)h2buf[1][k], a);
        headbuf[j] = sigm(a);
    }
    __syncthreads();
    if (j == 0){
        float a = b2[0];
        #pragma unroll
        for (int k = 0; k < 32; ++k) a = fmaf(W2[k], headbuf[k], a);
        out[b] = sigm(a);
    }
}

extern "C" void kernel_launch(void* const* d_in, const int* in_sizes, int n_in,
                              void* d_out, int out_size, void* d_ws, size_t ws_size,
                              hipStream_t stream)
{
    (void)in_sizes; (void)n_in; (void)d_ws; (void)ws_size; (void)out_size;
    lstm_mfma<<<NB, NT, 0, stream>>>(
        (const float*)d_in[0],
        (const float*)d_in[1], (const float*)d_in[2],
        (const float*)d_in[3], (const float*)d_in[4],
        (const float*)d_in[5], (const float*)d_in[6],
        (const float*)d_in[7], (const float*)d_in[8],
        (const float*)d_in[9], (const float*)d_in[10],
        (const float*)d_in[11], (const float*)d_in[12],
        (float*)d_out);
}